// Round 14
// baseline (111.859 us; speedup 1.0000x reference)
//
#include <hip/hip_runtime.h>
#include <hip/hip_bf16.h>

// SelfAttention: LN -> Q/K/V proj -> MHA (H=16, Dh=64) -> merge heads.
// B=2, T=2048, D=1024. fp32 in/out, bf16 MFMA compute.
// Attention v9: ZERO loop barriers. 1024 blocks x 256 thr; 4 waves/block =
// 2 q-subtiles x 2 kv-halves; each wave owns a private LDS slot (K[32][68],
// V^T[64][36], KVBLK=32) and streams its kv range independently (wave-private
// LDS needs only in-wave lgkmcnt ordering -> waves drift, phases interleave).
// Swapped QK^T 32x32x16, in-register P, no-max exp2 softmax (native v_exp).
// QKV GEMM: BM=64 BN=128 BK=64, T2 XOR-swizzle, global_load_lds staging.

typedef __attribute__((ext_vector_type(8)))  short short8;    // 8 bf16
typedef __attribute__((ext_vector_type(4)))  float f32x4;
typedef __attribute__((ext_vector_type(2)))  float f32x2;
typedef __attribute__((ext_vector_type(16))) float f32x16;
typedef __attribute__((ext_vector_type(2)))  unsigned int uint2v;

#define D_MODEL 1024
#define T_SEQ   2048
#define NHEAD   16
#define HDIM    64

#define LOG2E 1.4426950408889634f

#if defined(__has_builtin)
#if __has_builtin(__builtin_amdgcn_exp2f)
#define EXP2(x) __builtin_amdgcn_exp2f(x)
#endif
#if __has_builtin(__builtin_amdgcn_permlane32_swap)
#define HAVE_PERMSWAP 1
#endif
#endif
#ifndef EXP2
#define EXP2(x) exp2f(x)
#endif

__device__ __forceinline__ unsigned short f2bf(float x) {
    unsigned int u = __float_as_uint(x);
    u = (u + 0x7fffu + ((u >> 16) & 1u)) >> 16;   // RNE
    return (unsigned short)u;
}

__device__ __forceinline__ uint2v permswap(unsigned a, unsigned b) {
#ifdef HAVE_PERMSWAP
    return __builtin_amdgcn_permlane32_swap(a, b, false, false);
#else
    uint2v r;
    const unsigned as = (unsigned)__shfl_xor((int)a, 32, 64);
    const unsigned bs = (unsigned)__shfl_xor((int)b, 32, 64);
    const bool hi = (threadIdx.x & 32) != 0;
    r[0] = hi ? bs : a;
    r[1] = hi ? b  : as;
    return r;
#endif
}

__device__ __forceinline__ void w8(unsigned short* p, const uint4 v) {
    uint2 a; a.x = v.x; a.y = v.y;
    uint2 b; b.x = v.z; b.y = v.w;
    *(uint2*)p = a;
    *(uint2*)(p + 4) = b;
}

__device__ __forceinline__ short8 read8(const unsigned short* p) {
    union { unsigned u[4]; short8 s; } r;
    const uint2 a = *(const uint2*)p;
    const uint2 b = *(const uint2*)(p + 4);
    r.u[0] = a.x; r.u[1] = a.y; r.u[2] = b.x; r.u[3] = b.y;
    return r.s;
}

// ---------------- Fused LayerNorm + weight cast/transpose ----------------
// Blocks 0..4095: LN row -> bf16 xn. Blocks 4096..7167: W[k][n] f32 -> Wt[n][k] bf16.
__global__ __launch_bounds__(256) void ln_wcast_kernel(
    const float* __restrict__ x, const float* __restrict__ gam,
    const float* __restrict__ bet, unsigned short* __restrict__ xn,
    const float* __restrict__ Wq, const float* __restrict__ Wk,
    const float* __restrict__ Wv, unsigned short* __restrict__ Wt)
{
    __shared__ float red[8];
    __shared__ float tile[32][33];
    const int bid = blockIdx.x;
    if (bid < 4096) {
        const int row = bid;
        const int t = threadIdx.x;
        const float4 v = ((const float4*)(x + (size_t)row * D_MODEL))[t];
        float s  = v.x + v.y + v.z + v.w;
        float s2 = v.x * v.x + v.y * v.y + v.z * v.z + v.w * v.w;
#pragma unroll
        for (int off = 32; off; off >>= 1) {
            s  += __shfl_down(s,  off, 64);
            s2 += __shfl_down(s2, off, 64);
        }
        const int lane = t & 63, wave = t >> 6;
        if (lane == 0) { red[wave] = s; red[4 + wave] = s2; }
        __syncthreads();
        s  = red[0] + red[1] + red[2] + red[3];
        s2 = red[4] + red[5] + red[6] + red[7];
        const float mu   = s * (1.f / D_MODEL);
        const float var  = s2 * (1.f / D_MODEL) - mu * mu;
        const float rstd = rsqrtf(var + 1e-5f);
        const float4 gv = ((const float4*)gam)[t];
        const float4 bv = ((const float4*)bet)[t];
        ushort4 o;
        o.x = f2bf((v.x - mu) * rstd * gv.x + bv.x);
        o.y = f2bf((v.y - mu) * rstd * gv.y + bv.y);
        o.z = f2bf((v.z - mu) * rstd * gv.z + bv.z);
        o.w = f2bf((v.w - mu) * rstd * gv.w + bv.w);
        ((ushort4*)(xn + (size_t)row * D_MODEL))[t] = o;
    } else {
        const int id = bid - 4096;             // 0..3071
        const int z  = id >> 10;               // which W
        const int t2 = id & 1023;
        const int n0 = (t2 & 31) * 32, k0 = (t2 >> 5) * 32;
        const float* W = (z == 0) ? Wq : (z == 1) ? Wk : Wv;
        unsigned short* outw = Wt + (size_t)z * D_MODEL * D_MODEL;
        const int tx = threadIdx.x & 31, ty = threadIdx.x >> 5;
#pragma unroll
        for (int i = ty; i < 32; i += 8)
            tile[i][tx] = W[(size_t)(k0 + i) * D_MODEL + n0 + tx];
        __syncthreads();
#pragma unroll
        for (int i = ty; i < 32; i += 8)
            outw[(size_t)(n0 + i) * D_MODEL + k0 + tx] = f2bf(tile[tx][i]);
    }
}

// ------------- QKV GEMM v2: BM=64 BN=128 BK=64, grid 1536, XOR-swizzled LDS -------------
// which 0/1 (Q/K): C = xn . W^T -> bf16 [B,H,T,64]; Q scaled by 0.125*log2e.
// which 2  (V)  : operands swapped (A=Wv^T, B=xn) -> C' = V^T -> vt[b][m][t].
__global__ __launch_bounds__(256) void qkv_gemm_kernel(
    const unsigned short* __restrict__ xn, const unsigned short* __restrict__ Wt,
    const float* __restrict__ bq, const float* __restrict__ bk, const float* __restrict__ bv,
    unsigned short* __restrict__ qo, unsigned short* __restrict__ ko, unsigned short* __restrict__ vt)
{
    const int which = blockIdx.x >> 3;
    const int xt = blockIdx.x & 7, yt = blockIdx.y;
    const bool vmode = (which == 2);
    const unsigned short* Aptr = vmode ? (Wt + (size_t)2 * D_MODEL * D_MODEL) : xn;
    const unsigned short* Bptr = vmode ? xn : (Wt + (size_t)which * D_MODEL * D_MODEL);
    const float* bias   = (which == 0) ? bq : (which == 1) ? bk : bv;
    const float scale   = (which == 0) ? (0.125f * LOG2E) : 1.0f;
    const int m0 = vmode ? (yt & 15) * 64 : yt * 64;
    const int n0 = vmode ? (xt + (yt >> 4) * 8) * 128 : xt * 128;

    __shared__ unsigned short As[64][64];    // linear rows, content XOR-swizzled
    __shared__ unsigned short Bs[128][64];

    const int tid = threadIdx.x;
    const int lane = tid & 63, wave = tid >> 6;   // 4 waves, 1M x 4N
    const int wc = wave;                          // wave's 32-col slice of BN=128
    const int g = lane >> 4, c = lane & 15;

    const int srow = lane >> 3;                               // 0..7
    const int swzc = (((lane & 7) * 8) ^ ((srow & 7) * 8));   // pre-swizzled col
    const int rsw  = (c & 7) * 8;                             // read-side XOR

    f32x4 acc[4][2] = {};

    for (int kt = 0; kt < D_MODEL; kt += 64) {
        __syncthreads();   // previous tile fully consumed
#pragma unroll
        for (int i = 0; i < 2; ++i) {             // A: wave covers 16 rows
            const int r = wave * 16 + i * 8;
            const unsigned short* ga = Aptr + (size_t)(m0 + r + srow) * D_MODEL + kt + swzc;
            __builtin_amdgcn_global_load_lds(
                (const __attribute__((address_space(1))) unsigned int*)ga,
                (__attribute__((address_space(3))) unsigned int*)(&As[r][0]), 16, 0, 0);
        }
#pragma unroll
        for (int i = 0; i < 4; ++i) {             // B: wave covers 32 rows
            const int r = wave * 32 + i * 8;
            const unsigned short* gb = Bptr + (size_t)(n0 + r + srow) * D_MODEL + kt + swzc;
            __builtin_amdgcn_global_load_lds(
                (const __attribute__((address_space(1))) unsigned int*)gb,
                (__attribute__((address_space(3))) unsigned int*)(&Bs[r][0]), 16, 0, 0);
        }
        __syncthreads();   // vmcnt(0) drain + barrier -> LDS ready

        short8 af[4][2], bf[2][2];
#pragma unroll
        for (int i = 0; i < 4; ++i) {
            const int ra = i * 16 + c;            // ra&7 == c&7
#pragma unroll
            for (int kk = 0; kk < 2; ++kk)
                af[i][kk] = *(const short8*)(&As[ra][(kk * 32 + g * 8) ^ rsw]);
        }
#pragma unroll
        for (int j = 0; j < 2; ++j) {
            const int rb = wc * 32 + j * 16 + c;
#pragma unroll
            for (int kk = 0; kk < 2; ++kk)
                bf[j][kk] = *(const short8*)(&Bs[rb][(kk * 32 + g * 8) ^ rsw]);
        }
#pragma unroll
        for (int kk = 0; kk < 2; ++kk)
#pragma unroll
            for (int i = 0; i < 4; ++i)
#pragma unroll
                for (int j = 0; j < 2; ++j)
                    acc[i][j] = __builtin_amdgcn_mfma_f32_16x16x32_bf16(
                        af[i][kk], bf[j][kk], acc[i][j], 0, 0, 0);
    }

    if (!vmode) {
        unsigned short* out = (which == 0) ? qo : ko;
#pragma unroll
        for (int j = 0; j < 2; ++j) {
            const int n = n0 + wc * 32 + j * 16 + c;
            const float bn = bias[n];
            const int h = n >> 6, dh = n & 63;
#pragma unroll
            for (int i = 0; i < 4; ++i) {
#pragma unroll
                for (int r = 0; r < 4; ++r) {
                    const int m = m0 + i * 16 + g * 4 + r;   // m = b*2048 + t
                    const int bb = m >> 11, t = m & 2047;
                    out[((size_t)(bb * NHEAD + h) * T_SEQ + t) * HDIM + dh] =
                        f2bf((acc[i][j][r] + bn) * scale);
                }
            }
        }
    } else {
#pragma unroll
        for (int i = 0; i < 4; ++i) {
#pragma unroll
            for (int r = 0; r < 4; ++r) {
                const int m = m0 + i * 16 + g * 4 + r;       // weight-out 0..1023
                const float bn = bias[m];
#pragma unroll
                for (int j = 0; j < 2; ++j) {
                    const int n = n0 + wc * 32 + j * 16 + c; // token 0..4095
                    const int bb = n >> 11, t = n & 2047;
                    vt[(size_t)bb * (D_MODEL * T_SEQ) + (size_t)m * T_SEQ + t] =
                        f2bf(acc[i][j][r] + bn);
                }
            }
        }
    }
}

// ------------- Flash attention v9: barrier-free, wave-private LDS staging -------------
// Grid: 1024 blocks (32 q-tiles of 64 x 32 bh), XCD-chunk-swizzled, 256 threads.
// Wave w: q-subtile (w&1)*32, kv-half (w>>1)*1024; 32 KVBLK=32 tiles, private
// LDS slot, NO barriers in the loop (in-wave lgkm ordering only).
// S^T = mfma_32x32x16(K, Q); PV: O^T = mfma(V^T, P^T) with in-register P.
__global__ __launch_bounds__(256, 4) void attn_kernel(
    const unsigned short* __restrict__ qb, const unsigned short* __restrict__ kb,
    const unsigned short* __restrict__ vtb, float* __restrict__ out)
{
    const int id  = blockIdx.x;                  // 0..1023
    const int swz = (id & 7) * 128 + (id >> 3);  // XCD-chunked (1024 % 8 == 0)
    const int qt  = swz & 31;                    // q-tile of 64 rows
    const int bh  = swz >> 5;                    // 0..31
    const int b = bh >> 4, head = bh & 15;
    const unsigned short* Q  = qb  + (size_t)bh * T_SEQ * HDIM;
    const unsigned short* Kp = kb  + (size_t)bh * T_SEQ * HDIM;
    const unsigned short* Vt = vtb + (size_t)b * (D_MODEL * T_SEQ)
                                   + (size_t)head * (HDIM * T_SEQ);   // [64][2048]

    // Per wave (4480 ushorts = 8960 B): K[32][68] at +0, V^T[64][36] at +2176.
    // 4 waves = 35840 B. Epilogue overlay: obuf f32[64][68] + l_lds f32[64].
    __shared__ __align__(16) unsigned short smem[17920];

    const int tid = threadIdx.x, lane = tid & 63, wave = tid >> 6;
    const int w2 = wave & 1, kvh = wave >> 1;
    const int q = lane & 31, h = lane >> 5;
    const int kvbase = kvh * (T_SEQ / 2);

    unsigned short* kbuf = &smem[wave * 4480];
    unsigned short* vbuf = kbuf + 2176;

    const int krow = lane >> 3, kch = (lane & 7) * 8;   // K stage: 8 rows/instr
    const int vrow = lane >> 2, vch = (lane & 3) * 8;   // V stage: 16 rows/instr

    // Q fragments (B-operand): lane holds Q[q][k = c*16 + h*8 + j]
    short8 qf[4];
    {
        const unsigned short* qp = Q + (size_t)(qt * 64 + w2 * 32 + q) * HDIM;
#pragma unroll
        for (int c = 0; c < 4; ++c)
            qf[c] = *(const short8*)(qp + c * 16 + h * 8);
    }

    float l_r = 0.f;
    f32x16 o[2] = {};

    // prologue: tile 0 -> private LDS (in-wave vmcnt/lgkm ordering, no barrier)
    {
        const unsigned short* kp = Kp + (size_t)(kvbase + krow) * HDIM + kch;
        const unsigned short* vp = Vt + (size_t)vrow * T_SEQ + kvbase + vch;
        uint4 kr[4], vr[4];
#pragma unroll
        for (int i = 0; i < 4; ++i) kr[i] = *(const uint4*)(kp + (size_t)i * 8 * HDIM);
#pragma unroll
        for (int i = 0; i < 4; ++i) vr[i] = *(const uint4*)(vp + (size_t)i * 16 * T_SEQ);
#pragma unroll
        for (int i = 0; i < 4; ++i) w8(kbuf + (i * 8 + krow) * 68 + kch, kr[i]);
#pragma unroll
        for (int i = 0; i < 4; ++i) w8(vbuf + (i * 16 + vrow) * 36 + vch, vr[i]);
    }

#pragma unroll 1
    for (int t = 0; t < 32; ++t) {
        const bool more = (t + 1 < 32);
        const int kvn = kvbase + (t + 1) * 32;

        // prefetch next K tile into regs (written after QK reads complete)
        uint4 kr[4];
        if (more) {
            const unsigned short* kp = Kp + (size_t)(kvn + krow) * HDIM + kch;
#pragma unroll
            for (int i = 0; i < 4; ++i) kr[i] = *(const uint4*)(kp + (size_t)i * 8 * HDIM);
        }

        // S^T = K Q^T (one 32-kv block, K-dim 64 = 4 mfma)
        f32x16 s = {};
#pragma unroll
        for (int c = 0; c < 4; ++c) {
            const short8 kf = read8(kbuf + (size_t)q * 68 + c * 16 + h * 8);
            s = __builtin_amdgcn_mfma_f32_32x32x16_bf16(kf, qf[c], s, 0, 0, 0);
        }

        // P = exp2(S) raw (no max) -- native v_exp_f32
#pragma unroll
        for (int r = 0; r < 16; ++r) { s[r] = EXP2(s[r]); }

        // row sum, packed tree
        {
            f32x2 u[8];
#pragma unroll
            for (int r = 0; r < 8; ++r) { f32x2 a; a[0] = s[2*r]; a[1] = s[2*r+1]; u[r] = a; }
            u[0] += u[1]; u[2] += u[3]; u[4] += u[5]; u[6] += u[7];
            u[0] += u[2]; u[4] += u[6];
            u[0] += u[4];
            float rs = u[0][0] + u[0][1];
            rs += __shfl_xor(rs, 32, 64);
            l_r += rs;
        }

        // pack to bf16 words: Wb[2u+p] covers kv {8u+4h+2p, +1}
        unsigned Wb[8];
#pragma unroll
        for (int u = 0; u < 4; ++u) {
            asm("v_cvt_pk_bf16_f32 %0, %1, %2" : "=v"(Wb[u*2])   : "v"(s[4*u]),   "v"(s[4*u+1]));
            asm("v_cvt_pk_bf16_f32 %0, %1, %2" : "=v"(Wb[u*2+1]) : "v"(s[4*u+2]), "v"(s[4*u+3]));
        }

        // B-frags: pf[m] slot (h,j) = P[kv = 16m + 8h + j][q]
        short8 pf[2];
#pragma unroll
        for (int m = 0; m < 2; ++m) {
            const uint2v r0 = permswap(Wb[4*m],     Wb[4*m + 2]);
            const uint2v r1 = permswap(Wb[4*m + 1], Wb[4*m + 3]);
            union { unsigned u[4]; short8 s; } pw;
            pw.u[0] = r0[0]; pw.u[1] = r1[0]; pw.u[2] = r0[1]; pw.u[3] = r1[1];
            pf[m] = pw.s;
        }

        // K tile reads done -> overwrite K slot with next tile (in-wave order)
        if (more) {
#pragma unroll
            for (int i = 0; i < 4; ++i) w8(kbuf + (i * 8 + krow) * 68 + kch, kr[i]);
        }
        // issue next V loads; written after PV reads complete
        uint4 vr[4];
        if (more) {
            const unsigned short* vp = Vt + (size_t)vrow * T_SEQ + kvn + vch;
#pragma unroll
            for (int i = 0; i < 4; ++i) vr[i] = *(const uint4*)(vp + (size_t)i * 16 * T_SEQ);
        }

        // O^T += V^T P^T
#pragma unroll
        for (int dt = 0; dt < 2; ++dt) {
#pragma unroll
            for (int kk = 0; kk < 2; ++kk) {
                const short8 vf = read8(vbuf + (size_t)(dt * 32 + q) * 36 + kk * 16 + h * 8);
                o[dt] = __builtin_amdgcn_mfma_f32_32x32x16_bf16(vf, pf[kk], o[dt], 0, 0, 0);
            }
        }

        if (more) {
#pragma unroll
            for (int i = 0; i < 4; ++i) w8(vbuf + (i * 16 + vrow) * 36 + vch, vr[i]);
        }
    }

    // ---- merge the two kv halves (only barriers in the kernel) ----
    __syncthreads();                                   // all waves' loop LDS done
    float* obuf  = (float*)(void*)smem;                // [64][68] f32
    float* l_lds = ((float*)(void*)smem) + 64 * 68;    // [64] f32

    const int qrl = w2 * 32 + q;                       // local q row 0..63
    if (kvh == 0) {                                    // write raw numerators + l_A
#pragma unroll
        for (int dt = 0; dt < 2; ++dt)
#pragma unroll
            for (int u = 0; u < 4; ++u) {
                float* dst = obuf + (size_t)qrl * 68 + dt * 32 + 8 * u + 4 * h;
                float2 lo; lo.x = o[dt][4*u];     lo.y = o[dt][4*u + 1];
                float2 hi; hi.x = o[dt][4*u + 2]; hi.y = o[dt][4*u + 3];
                *(float2*)dst = lo;
                *(float2*)(dst + 2) = hi;
            }
        if (h == 0) l_lds[qrl] = l_r;
    }
    __syncthreads();
    if (kvh == 1) {                                    // add numerator, scale by 1/(lA+lB)
        const float invl = 1.0f / (l_lds[qrl] + l_r);
#pragma unroll
        for (int dt = 0; dt < 2; ++dt)
#pragma unroll
            for (int u = 0; u < 4; ++u) {
                float* dst = obuf + (size_t)qrl * 68 + dt * 32 + 8 * u + 4 * h;
                float2 lo = *(const float2*)dst;
                float2 hi = *(const float2*)(dst + 2);
                lo.x = (lo.x + o[dt][4*u])     * invl;
                lo.y = (lo.y + o[dt][4*u + 1]) * invl;
                hi.x = (hi.x + o[dt][4*u + 2]) * invl;
                hi.y = (hi.y + o[dt][4*u + 3]) * invl;
                *(float2*)dst = lo;
                *(float2*)(dst + 2) = hi;
            }
    }
    __syncthreads();
#pragma unroll
    for (int it = 0; it < 2; ++it) {
        const int row = it * 32 + (tid >> 3);          // 0..63
        const int col = (tid & 7) * 8;                 // 0..56
        const float4 v0 = *(const float4*)(&obuf[(size_t)row * 68 + col]);
        const float4 v1 = *(const float4*)(&obuf[(size_t)row * 68 + col + 4]);
        float* op = &out[(size_t)(b * T_SEQ + qt * 64 + row) * D_MODEL + head * HDIM + col];
        *(float4*)op = v0;
        *(float4*)(op + 4) = v1;
    }
}

extern "C" void kernel_launch(void* const* d_in, const int* in_sizes, int n_in,
                              void* d_out, int out_size, void* d_ws, size_t ws_size,
                              hipStream_t stream)
{
    const float* x   = (const float*)d_in[0];
    const float* lng = (const float*)d_in[1];
    const float* lnb = (const float*)d_in[2];
    const float* Wq  = (const float*)d_in[3];
    const float* bq  = (const float*)d_in[4];
    const float* Wk  = (const float*)d_in[5];
    const float* bk  = (const float*)d_in[6];
    const float* Wv  = (const float*)d_in[7];
    const float* bv  = (const float*)d_in[8];
    float* out = (float*)d_out;

    // workspace layout (bf16), ~38 MB total
    unsigned short* xn = (unsigned short*)d_ws;                 // [4096][1024]
    unsigned short* Wt = xn + (size_t)4096 * 1024;              // 3 x [1024][1024] (transposed)
    unsigned short* qh = Wt + (size_t)3 * 1024 * 1024;          // [B,H,T,64]
    unsigned short* kh = qh + (size_t)4096 * 1024;
    unsigned short* vt = kh + (size_t)4096 * 1024;              // [B][1024][2048] = V^T

    ln_wcast_kernel<<<7168, 256, 0, stream>>>(x, lng, lnb, xn, Wq, Wk, Wv, Wt);
    qkv_gemm_kernel<<<dim3(24, 64), 256, 0, stream>>>(xn, Wt, bq, bk, bv, qh, kh, vt);
    attn_kernel<<<1024, 256, 0, stream>>>(qh, kh, vt, out);
}

// Round 15
// 105.582 us; speedup vs baseline: 1.0594x; 1.0594x over previous
//
#include <hip/hip_runtime.h>
#include <hip/hip_bf16.h>

// SelfAttention: LN -> Q/K/V proj -> MHA (H=16, Dh=64) -> merge heads.
// B=2, T=2048, D=1024. fp32 in/out, bf16 MFMA compute.
// Attention (v5 + native exp2 + MFMA-l): swapped QK^T, 32x32x16 MFMA,
// in-register P, no-max exp2 softmax; denominator l computed on the MFMA
// pipe via mfma(ones, P) accumulation (removes VALU sum tree + shfl).
// KV-split wave-groups, dbuf LDS, lgkm-only barrier.
// QKV GEMM: BM=64 BN=128 BK=64, T2 XOR-swizzle, global_load_lds staging.

typedef __attribute__((ext_vector_type(8)))  short short8;    // 8 bf16
typedef __attribute__((ext_vector_type(4)))  float f32x4;
typedef __attribute__((ext_vector_type(2)))  float f32x2;
typedef __attribute__((ext_vector_type(16))) float f32x16;
typedef __attribute__((ext_vector_type(2)))  unsigned int uint2v;

#define D_MODEL 1024
#define T_SEQ   2048
#define NHEAD   16
#define HDIM    64

#define LOG2E 1.4426950408889634f

#if defined(__has_builtin)
#if __has_builtin(__builtin_amdgcn_exp2f)
#define EXP2(x) __builtin_amdgcn_exp2f(x)
#endif
#if __has_builtin(__builtin_amdgcn_permlane32_swap)
#define HAVE_PERMSWAP 1
#endif
#endif
#ifndef EXP2
#define EXP2(x) exp2f(x)
#endif

__device__ __forceinline__ unsigned short f2bf(float x) {
    unsigned int u = __float_as_uint(x);
    u = (u + 0x7fffu + ((u >> 16) & 1u)) >> 16;   // RNE
    return (unsigned short)u;
}

__device__ __forceinline__ uint2v permswap(unsigned a, unsigned b) {
#ifdef HAVE_PERMSWAP
    return __builtin_amdgcn_permlane32_swap(a, b, false, false);
#else
    uint2v r;
    const unsigned as = (unsigned)__shfl_xor((int)a, 32, 64);
    const unsigned bs = (unsigned)__shfl_xor((int)b, 32, 64);
    const bool hi = (threadIdx.x & 32) != 0;
    r[0] = hi ? bs : a;
    r[1] = hi ? b  : as;
    return r;
#endif
}

// Barrier that does NOT drain vmcnt: LDS producer/consumer ordering only.
__device__ __forceinline__ void group_barrier() {
    asm volatile("s_waitcnt lgkmcnt(0)" ::: "memory");
    __builtin_amdgcn_s_barrier();
    asm volatile("" ::: "memory");
}

__device__ __forceinline__ void w8(unsigned short* p, const uint4 v) {
    uint2 a; a.x = v.x; a.y = v.y;
    uint2 b; b.x = v.z; b.y = v.w;
    *(uint2*)p = a;
    *(uint2*)(p + 4) = b;
}

__device__ __forceinline__ short8 read8(const unsigned short* p) {
    union { unsigned u[4]; short8 s; } r;
    const uint2 a = *(const uint2*)p;
    const uint2 b = *(const uint2*)(p + 4);
    r.u[0] = a.x; r.u[1] = a.y; r.u[2] = b.x; r.u[3] = b.y;
    return r.s;
}

// ---------------- Fused LayerNorm + weight cast/transpose ----------------
// Blocks 0..4095: LN row -> bf16 xn. Blocks 4096..7167: W[k][n] f32 -> Wt[n][k] bf16.
__global__ __launch_bounds__(256) void ln_wcast_kernel(
    const float* __restrict__ x, const float* __restrict__ gam,
    const float* __restrict__ bet, unsigned short* __restrict__ xn,
    const float* __restrict__ Wq, const float* __restrict__ Wk,
    const float* __restrict__ Wv, unsigned short* __restrict__ Wt)
{
    __shared__ float red[8];
    __shared__ float tile[32][33];
    const int bid = blockIdx.x;
    if (bid < 4096) {
        const int row = bid;
        const int t = threadIdx.x;
        const float4 v = ((const float4*)(x + (size_t)row * D_MODEL))[t];
        float s  = v.x + v.y + v.z + v.w;
        float s2 = v.x * v.x + v.y * v.y + v.z * v.z + v.w * v.w;
#pragma unroll
        for (int off = 32; off; off >>= 1) {
            s  += __shfl_down(s,  off, 64);
            s2 += __shfl_down(s2, off, 64);
        }
        const int lane = t & 63, wave = t >> 6;
        if (lane == 0) { red[wave] = s; red[4 + wave] = s2; }
        __syncthreads();
        s  = red[0] + red[1] + red[2] + red[3];
        s2 = red[4] + red[5] + red[6] + red[7];
        const float mu   = s * (1.f / D_MODEL);
        const float var  = s2 * (1.f / D_MODEL) - mu * mu;
        const float rstd = rsqrtf(var + 1e-5f);
        const float4 gv = ((const float4*)gam)[t];
        const float4 bv = ((const float4*)bet)[t];
        ushort4 o;
        o.x = f2bf((v.x - mu) * rstd * gv.x + bv.x);
        o.y = f2bf((v.y - mu) * rstd * gv.y + bv.y);
        o.z = f2bf((v.z - mu) * rstd * gv.z + bv.z);
        o.w = f2bf((v.w - mu) * rstd * gv.w + bv.w);
        ((ushort4*)(xn + (size_t)row * D_MODEL))[t] = o;
    } else {
        const int id = bid - 4096;             // 0..3071
        const int z  = id >> 10;               // which W
        const int t2 = id & 1023;
        const int n0 = (t2 & 31) * 32, k0 = (t2 >> 5) * 32;
        const float* W = (z == 0) ? Wq : (z == 1) ? Wk : Wv;
        unsigned short* outw = Wt + (size_t)z * D_MODEL * D_MODEL;
        const int tx = threadIdx.x & 31, ty = threadIdx.x >> 5;
#pragma unroll
        for (int i = ty; i < 32; i += 8)
            tile[i][tx] = W[(size_t)(k0 + i) * D_MODEL + n0 + tx];
        __syncthreads();
#pragma unroll
        for (int i = ty; i < 32; i += 8)
            outw[(size_t)(n0 + i) * D_MODEL + k0 + tx] = f2bf(tile[tx][i]);
    }
}

// ------------- QKV GEMM v2: BM=64 BN=128 BK=64, grid 1536, XOR-swizzled LDS -------------
// which 0/1 (Q/K): C = xn . W^T -> bf16 [B,H,T,64]; Q scaled by 0.125*log2e.
// which 2  (V)  : operands swapped (A=Wv^T, B=xn) -> C' = V^T -> vt[b][m][t].
__global__ __launch_bounds__(256) void qkv_gemm_kernel(
    const unsigned short* __restrict__ xn, const unsigned short* __restrict__ Wt,
    const float* __restrict__ bq, const float* __restrict__ bk, const float* __restrict__ bv,
    unsigned short* __restrict__ qo, unsigned short* __restrict__ ko, unsigned short* __restrict__ vt)
{
    const int which = blockIdx.x >> 3;
    const int xt = blockIdx.x & 7, yt = blockIdx.y;
    const bool vmode = (which == 2);
    const unsigned short* Aptr = vmode ? (Wt + (size_t)2 * D_MODEL * D_MODEL) : xn;
    const unsigned short* Bptr = vmode ? xn : (Wt + (size_t)which * D_MODEL * D_MODEL);
    const float* bias   = (which == 0) ? bq : (which == 1) ? bk : bv;
    const float scale   = (which == 0) ? (0.125f * LOG2E) : 1.0f;
    const int m0 = vmode ? (yt & 15) * 64 : yt * 64;
    const int n0 = vmode ? (xt + (yt >> 4) * 8) * 128 : xt * 128;

    __shared__ unsigned short As[64][64];    // linear rows, content XOR-swizzled
    __shared__ unsigned short Bs[128][64];

    const int tid = threadIdx.x;
    const int lane = tid & 63, wave = tid >> 6;   // 4 waves, 1M x 4N
    const int wc = wave;                          // wave's 32-col slice of BN=128
    const int g = lane >> 4, c = lane & 15;

    const int srow = lane >> 3;                               // 0..7
    const int swzc = (((lane & 7) * 8) ^ ((srow & 7) * 8));   // pre-swizzled col
    const int rsw  = (c & 7) * 8;                             // read-side XOR

    f32x4 acc[4][2] = {};

    for (int kt = 0; kt < D_MODEL; kt += 64) {
        __syncthreads();   // previous tile fully consumed
#pragma unroll
        for (int i = 0; i < 2; ++i) {             // A: wave covers 16 rows
            const int r = wave * 16 + i * 8;
            const unsigned short* ga = Aptr + (size_t)(m0 + r + srow) * D_MODEL + kt + swzc;
            __builtin_amdgcn_global_load_lds(
                (const __attribute__((address_space(1))) unsigned int*)ga,
                (__attribute__((address_space(3))) unsigned int*)(&As[r][0]), 16, 0, 0);
        }
#pragma unroll
        for (int i = 0; i < 4; ++i) {             // B: wave covers 32 rows
            const int r = wave * 32 + i * 8;
            const unsigned short* gb = Bptr + (size_t)(n0 + r + srow) * D_MODEL + kt + swzc;
            __builtin_amdgcn_global_load_lds(
                (const __attribute__((address_space(1))) unsigned int*)gb,
                (__attribute__((address_space(3))) unsigned int*)(&Bs[r][0]), 16, 0, 0);
        }
        __syncthreads();   // vmcnt(0) drain + barrier -> LDS ready

        short8 af[4][2], bf[2][2];
#pragma unroll
        for (int i = 0; i < 4; ++i) {
            const int ra = i * 16 + c;            // ra&7 == c&7
#pragma unroll
            for (int kk = 0; kk < 2; ++kk)
                af[i][kk] = *(const short8*)(&As[ra][(kk * 32 + g * 8) ^ rsw]);
        }
#pragma unroll
        for (int j = 0; j < 2; ++j) {
            const int rb = wc * 32 + j * 16 + c;
#pragma unroll
            for (int kk = 0; kk < 2; ++kk)
                bf[j][kk] = *(const short8*)(&Bs[rb][(kk * 32 + g * 8) ^ rsw]);
        }
#pragma unroll
        for (int kk = 0; kk < 2; ++kk)
#pragma unroll
            for (int i = 0; i < 4; ++i)
#pragma unroll
                for (int j = 0; j < 2; ++j)
                    acc[i][j] = __builtin_amdgcn_mfma_f32_16x16x32_bf16(
                        af[i][kk], bf[j][kk], acc[i][j], 0, 0, 0);
    }

    if (!vmode) {
        unsigned short* out = (which == 0) ? qo : ko;
#pragma unroll
        for (int j = 0; j < 2; ++j) {
            const int n = n0 + wc * 32 + j * 16 + c;
            const float bn = bias[n];
            const int h = n >> 6, dh = n & 63;
#pragma unroll
            for (int i = 0; i < 4; ++i) {
#pragma unroll
                for (int r = 0; r < 4; ++r) {
                    const int m = m0 + i * 16 + g * 4 + r;   // m = b*2048 + t
                    const int bb = m >> 11, t = m & 2047;
                    out[((size_t)(bb * NHEAD + h) * T_SEQ + t) * HDIM + dh] =
                        f2bf((acc[i][j][r] + bn) * scale);
                }
            }
        }
    } else {
#pragma unroll
        for (int i = 0; i < 4; ++i) {
#pragma unroll
            for (int r = 0; r < 4; ++r) {
                const int m = m0 + i * 16 + g * 4 + r;       // weight-out 0..1023
                const float bn = bias[m];
#pragma unroll
                for (int j = 0; j < 2; ++j) {
                    const int n = n0 + wc * 32 + j * 16 + c; // token 0..4095
                    const int bb = n >> 11, t = n & 2047;
                    vt[(size_t)bb * (D_MODEL * T_SEQ) + (size_t)m * T_SEQ + t] =
                        f2bf(acc[i][j][r] + bn);
                }
            }
        }
    }
}

// ------------- Flash attention v5 + MFMA-l: KV-split + lgkm-only barrier -------------
// Grid: 512 blocks (16 q-tiles x 32 bh), XCD-chunk-swizzled, 512 threads (8 waves).
// Waves 0-3: kv in [0,1024); waves 4-7: kv in [1024,2048); same 128 q rows.
// S^T = mfma_32x32x16(K, Q); PV: O^T = mfma(V^T, P^T); l = mfma(ones, P^T)
// accumulated on the matrix pipe (every D row = l[q]; no VALU tree, no shfl).
__global__ __launch_bounds__(512, 4) void attn_kernel(
    const unsigned short* __restrict__ qb, const unsigned short* __restrict__ kb,
    const unsigned short* __restrict__ vtb, float* __restrict__ out)
{
    const int id  = blockIdx.x;                 // 0..511
    const int swz = (id & 7) * 64 + (id >> 3);  // XCD-chunked (512 % 8 == 0)
    const int qt  = swz & 15;                   // q-tile of 128 rows
    const int bh  = swz >> 4;                   // 0..31
    const int b = bh >> 4, head = bh & 15;
    const unsigned short* Q  = qb  + (size_t)bh * T_SEQ * HDIM;
    const unsigned short* Kp = kb  + (size_t)bh * T_SEQ * HDIM;
    const unsigned short* Vt = vtb + (size_t)b * (D_MODEL * T_SEQ)
                                   + (size_t)head * (HDIM * T_SEQ);   // [64][2048]

    __shared__ __align__(16) unsigned short smem[34816];

    const int tid = threadIdx.x, lane = tid & 63, wave = tid >> 6;
    const int grp = wave >> 2, w4 = wave & 3;
    const int q = lane & 31, h = lane >> 5;
    const int kvbase = grp * (T_SEQ / 2);

    const int gtid = tid & 255;
    const int sr = gtid >> 3;            // staging row 0..31 (+32 for 2nd chunk)
    const int sc = (gtid & 7) * 8;       // staging col (elements)

    unsigned short* gbase = &smem[grp * 17408];

    // Q fragments (B-operand): lane holds Q[q][k = c*16 + h*8 + j]
    short8 qf[4];
    {
        const unsigned short* qp = Q + (size_t)(qt * 128 + w4 * 32 + q) * HDIM;
#pragma unroll
        for (int c = 0; c < 4; ++c)
            qf[c] = *(const short8*)(qp + c * 16 + h * 8);
    }

    // ones A-fragment for the l-accumulating MFMA (layout-independent)
    union { unsigned u[4]; short8 s; } ones_u;
    ones_u.u[0] = ones_u.u[1] = ones_u.u[2] = ones_u.u[3] = 0x3F803F80u;
    const short8 ones8 = ones_u.s;

    f32x16 o[2] = {};
    f32x16 o_l = {};            // every row of D = sum_kv P[kv][q] = l[q]

    // prologue: group's tile 0 -> regs -> buf 0
    const unsigned short* kp0 = Kp + (size_t)(kvbase + sr) * HDIM + sc;
    const unsigned short* vp0 = Vt + (size_t)sr * T_SEQ + kvbase + sc;
    uint4 kr0 = *(const uint4*)(kp0);
    uint4 kr1 = *(const uint4*)(kp0 + 32 * HDIM);
    uint4 vr0 = *(const uint4*)(vp0);
    uint4 vr1 = *(const uint4*)(vp0 + 32 * T_SEQ);
    w8(gbase + sr * 68 + sc, kr0);
    w8(gbase + (sr + 32) * 68 + sc, kr1);
    w8(gbase + 8704 + sr * 68 + sc, vr0);
    w8(gbase + 8704 + (sr + 32) * 68 + sc, vr1);
    kp0 += 64 * HDIM;
    vp0 += 64;

    int cur = 0;
#pragma unroll 1
    for (int t = 0; t < 16; ++t) {
        const bool more = (t + 1 < 16);
        if (more) {   // issue next-tile loads; they stay in flight across barrier
            kr0 = *(const uint4*)(kp0);
            kr1 = *(const uint4*)(kp0 + 32 * HDIM);
            vr0 = *(const uint4*)(vp0);
            vr1 = *(const uint4*)(vp0 + 32 * T_SEQ);
            kp0 += 64 * HDIM;
            vp0 += 64;
        }
        group_barrier();                       // lgkm drain only: buf[cur] ready
        const unsigned short* kbuf = gbase + cur * 4352;
        const unsigned short* vbuf = gbase + 8704 + cur * 4352;

        // S^T = K Q^T (two 32-kv blocks)
        f32x16 s0 = {}, s1 = {};
        __builtin_amdgcn_s_setprio(1);
#pragma unroll
        for (int c = 0; c < 4; ++c) {
            const short8 kf0 = read8(kbuf + (size_t)q * 68 + c * 16 + h * 8);
            const short8 kf1 = read8(kbuf + (size_t)(32 + q) * 68 + c * 16 + h * 8);
            s0 = __builtin_amdgcn_mfma_f32_32x32x16_bf16(kf0, qf[c], s0, 0, 0, 0);
            s1 = __builtin_amdgcn_mfma_f32_32x32x16_bf16(kf1, qf[c], s1, 0, 0, 0);
        }
        __builtin_amdgcn_s_setprio(0);

        // P = exp2(S) raw (no max) -- native v_exp_f32
#pragma unroll
        for (int r = 0; r < 16; ++r) { s0[r] = EXP2(s0[r]); }
#pragma unroll
        for (int r = 0; r < 16; ++r) { s1[r] = EXP2(s1[r]); }

        // pack to bf16 words: W[u*2+p] covers kv32 {8u+4h+2p, +1}
        unsigned Wb0[8], Wb1[8];
#pragma unroll
        for (int u = 0; u < 4; ++u) {
            asm("v_cvt_pk_bf16_f32 %0, %1, %2" : "=v"(Wb0[u*2])   : "v"(s0[4*u]),   "v"(s0[4*u+1]));
            asm("v_cvt_pk_bf16_f32 %0, %1, %2" : "=v"(Wb0[u*2+1]) : "v"(s0[4*u+2]), "v"(s0[4*u+3]));
            asm("v_cvt_pk_bf16_f32 %0, %1, %2" : "=v"(Wb1[u*2])   : "v"(s1[4*u]),   "v"(s1[4*u+1]));
            asm("v_cvt_pk_bf16_f32 %0, %1, %2" : "=v"(Wb1[u*2+1]) : "v"(s1[4*u+2]), "v"(s1[4*u+3]));
        }

        // B-frags: pf[2b+m] slot (h,j) = P[kv = 16*(2b+m) + 8h + j][q]
        short8 pf[4];
#pragma unroll
        for (int m = 0; m < 2; ++m) {
            {
                const uint2v r0 = permswap(Wb0[4*m],     Wb0[4*m + 2]);
                const uint2v r1 = permswap(Wb0[4*m + 1], Wb0[4*m + 3]);
                union { unsigned u[4]; short8 s; } pw;
                pw.u[0] = r0[0]; pw.u[1] = r1[0]; pw.u[2] = r0[1]; pw.u[3] = r1[1];
                pf[m] = pw.s;
            }
            {
                const uint2v r0 = permswap(Wb1[4*m],     Wb1[4*m + 2]);
                const uint2v r1 = permswap(Wb1[4*m + 1], Wb1[4*m + 3]);
                union { unsigned u[4]; short8 s; } pw;
                pw.u[0] = r0[0]; pw.u[1] = r1[0]; pw.u[2] = r0[1]; pw.u[3] = r1[1];
                pf[2 + m] = pw.s;
            }
        }

        // O^T += V^T P^T ; l += 1 . P^T  (all on the matrix pipe)
        __builtin_amdgcn_s_setprio(1);
#pragma unroll
        for (int cp = 0; cp < 4; ++cp) {
            const short8 vf0 = read8(vbuf + (size_t)q * 68 + cp * 16 + h * 8);
            const short8 vf1 = read8(vbuf + (size_t)(32 + q) * 68 + cp * 16 + h * 8);
            o[0] = __builtin_amdgcn_mfma_f32_32x32x16_bf16(vf0, pf[cp], o[0], 0, 0, 0);
            o[1] = __builtin_amdgcn_mfma_f32_32x32x16_bf16(vf1, pf[cp], o[1], 0, 0, 0);
            o_l  = __builtin_amdgcn_mfma_f32_32x32x16_bf16(ones8, pf[cp], o_l, 0, 0, 0);
        }
        __builtin_amdgcn_s_setprio(0);

        if (more) {   // vmcnt wait lands here (compiler), not at the barrier
            unsigned short* kd = gbase + (cur ^ 1) * 4352;
            unsigned short* vd = gbase + 8704 + (cur ^ 1) * 4352;
            w8(kd + sr * 68 + sc, kr0);
            w8(kd + (sr + 32) * 68 + sc, kr1);
            w8(vd + sr * 68 + sc, vr0);
            w8(vd + (sr + 32) * 68 + sc, vr1);
        }
        cur ^= 1;
    }

    const float l_r = o_l[0];                          // l[q] (any row)

    // ---- merge the two KV halves, then transpose-store ----
    __syncthreads();                                   // all LDS reads done
    float* obuf  = (float*)(void*)smem;                // [128][68] f32
    float* l_lds = ((float*)(void*)smem) + 128 * 68;   // [128] f32

    const int qrl = w4 * 32 + q;                       // local q row 0..127
    if (grp == 0) {                                    // write raw numerators + l_A
#pragma unroll
        for (int dt = 0; dt < 2; ++dt)
#pragma unroll
            for (int u = 0; u < 4; ++u) {
                float* dst = obuf + (size_t)qrl * 68 + dt * 32 + 8 * u + 4 * h;
                float2 lo; lo.x = o[dt][4*u];     lo.y = o[dt][4*u + 1];
                float2 hi; hi.x = o[dt][4*u + 2]; hi.y = o[dt][4*u + 3];
                *(float2*)dst = lo;
                *(float2*)(dst + 2) = hi;
            }
        if (h == 0) l_lds[qrl] = l_r;
    }
    __syncthreads();
    if (grp == 1) {                                    // add numerator, scale by 1/(lA+lB)
        const float invl = 1.0f / (l_lds[qrl] + l_r);
#pragma unroll
        for (int dt = 0; dt < 2; ++dt)
#pragma unroll
            for (int u = 0; u < 4; ++u) {
                float* dst = obuf + (size_t)qrl * 68 + dt * 32 + 8 * u + 4 * h;
                float2 lo = *(const float2*)dst;
                float2 hi = *(const float2*)(dst + 2);
                lo.x = (lo.x + o[dt][4*u])     * invl;
                lo.y = (lo.y + o[dt][4*u + 1]) * invl;
                hi.x = (hi.x + o[dt][4*u + 2]) * invl;
                hi.y = (hi.y + o[dt][4*u + 3]) * invl;
                *(float2*)dst = lo;
                *(float2*)(dst + 2) = hi;
            }
    }
    __syncthreads();
#pragma unroll
    for (int it = 0; it < 4; ++it) {
        const int row = it * 32 + (tid >> 4);          // 0..127
        const int col = (tid & 15) * 4;                // 0..60
        const float4 v = *(const float4*)(&obuf[(size_t)row * 68 + col]);
        *(float4*)(&out[(size_t)(b * T_SEQ + qt * 128 + row) * D_MODEL + head * HDIM + col]) = v;
    }
}

extern "C" void kernel_launch(void* const* d_in, const int* in_sizes, int n_in,
                              void* d_out, int out_size, void* d_ws, size_t ws_size,
                              hipStream_t stream)
{
    const float* x   = (const float*)d_in[0];
    const float* lng = (const float*)d_in[1];
    const float* lnb = (const float*)d_in[2];
    const float* Wq  = (const float*)d_in[3];
    const float* bq  = (const float*)d_in[4];
    const float* Wk  = (const float*)d_in[5];
    const float* bk  = (const float*)d_in[6];
    const float* Wv  = (const float*)d_in[7];
    const float* bv  = (const float*)d_in[8];
    float* out = (float*)d_out;

    // workspace layout (bf16), ~38 MB total
    unsigned short* xn = (unsigned short*)d_ws;                 // [4096][1024]
    unsigned short* Wt = xn + (size_t)4096 * 1024;              // 3 x [1024][1024] (transposed)
    unsigned short* qh = Wt + (size_t)3 * 1024 * 1024;          // [B,H,T,64]
    unsigned short* kh = qh + (size_t)4096 * 1024;
    unsigned short* vt = kh + (size_t)4096 * 1024;              // [B][1024][2048] = V^T

    ln_wcast_kernel<<<7168, 256, 0, stream>>>(x, lng, lnb, xn, Wq, Wk, Wv, Wt);
    qkv_gemm_kernel<<<dim3(24, 64), 256, 0, stream>>>(xn, Wt, bq, bk, bv, qh, kh, vt);
    attn_kernel<<<512, 512, 0, stream>>>(qh, kh, vt, out);
}

// Round 16
// 95.946 us; speedup vs baseline: 1.1659x; 1.1004x over previous
//
#include <hip/hip_runtime.h>
#include <hip/hip_bf16.h>

// SelfAttention: LN -> Q/K/V proj -> MHA (H=16, Dh=64) -> merge heads.
// B=2, T=2048, D=1024. fp32 in/out, bf16 MFMA compute.
// Attention (v5 + native exp2, proven 48.5us): swapped QK^T, 32x32x16 MFMA,
// in-register P, no-max exp2 softmax, KV-split wave-groups, dbuf LDS.
// QKV GEMM v3: BM=64 BN=128 BK=64 + DOUBLE-BUFFERED LDS 2-phase schedule
// (T3-minimum): issue next-tile global_load_lds BEFORE this tile's MFMA;
// single __syncthreads() per K-step drains vmcnt after compute has hidden it.

typedef __attribute__((ext_vector_type(8)))  short short8;    // 8 bf16
typedef __attribute__((ext_vector_type(4)))  float f32x4;
typedef __attribute__((ext_vector_type(2)))  float f32x2;
typedef __attribute__((ext_vector_type(16))) float f32x16;
typedef __attribute__((ext_vector_type(2)))  unsigned int uint2v;

#define D_MODEL 1024
#define T_SEQ   2048
#define NHEAD   16
#define HDIM    64

#define LOG2E 1.4426950408889634f

#if defined(__has_builtin)
#if __has_builtin(__builtin_amdgcn_exp2f)
#define EXP2(x) __builtin_amdgcn_exp2f(x)
#endif
#if __has_builtin(__builtin_amdgcn_permlane32_swap)
#define HAVE_PERMSWAP 1
#endif
#endif
#ifndef EXP2
#define EXP2(x) exp2f(x)
#endif

__device__ __forceinline__ unsigned short f2bf(float x) {
    unsigned int u = __float_as_uint(x);
    u = (u + 0x7fffu + ((u >> 16) & 1u)) >> 16;   // RNE
    return (unsigned short)u;
}

__device__ __forceinline__ uint2v permswap(unsigned a, unsigned b) {
#ifdef HAVE_PERMSWAP
    return __builtin_amdgcn_permlane32_swap(a, b, false, false);
#else
    uint2v r;
    const unsigned as = (unsigned)__shfl_xor((int)a, 32, 64);
    const unsigned bs = (unsigned)__shfl_xor((int)b, 32, 64);
    const bool hi = (threadIdx.x & 32) != 0;
    r[0] = hi ? bs : a;
    r[1] = hi ? b  : as;
    return r;
#endif
}

// Barrier that does NOT drain vmcnt: LDS producer/consumer ordering only.
__device__ __forceinline__ void group_barrier() {
    asm volatile("s_waitcnt lgkmcnt(0)" ::: "memory");
    __builtin_amdgcn_s_barrier();
    asm volatile("" ::: "memory");
}

__device__ __forceinline__ void w8(unsigned short* p, const uint4 v) {
    uint2 a; a.x = v.x; a.y = v.y;
    uint2 b; b.x = v.z; b.y = v.w;
    *(uint2*)p = a;
    *(uint2*)(p + 4) = b;
}

__device__ __forceinline__ short8 read8(const unsigned short* p) {
    union { unsigned u[4]; short8 s; } r;
    const uint2 a = *(const uint2*)p;
    const uint2 b = *(const uint2*)(p + 4);
    r.u[0] = a.x; r.u[1] = a.y; r.u[2] = b.x; r.u[3] = b.y;
    return r.s;
}

// ---------------- Fused LayerNorm + weight cast/transpose ----------------
// Blocks 0..4095: LN row -> bf16 xn. Blocks 4096..7167: W[k][n] f32 -> Wt[n][k] bf16.
__global__ __launch_bounds__(256) void ln_wcast_kernel(
    const float* __restrict__ x, const float* __restrict__ gam,
    const float* __restrict__ bet, unsigned short* __restrict__ xn,
    const float* __restrict__ Wq, const float* __restrict__ Wk,
    const float* __restrict__ Wv, unsigned short* __restrict__ Wt)
{
    __shared__ float red[8];
    __shared__ float tile[32][33];
    const int bid = blockIdx.x;
    if (bid < 4096) {
        const int row = bid;
        const int t = threadIdx.x;
        const float4 v = ((const float4*)(x + (size_t)row * D_MODEL))[t];
        float s  = v.x + v.y + v.z + v.w;
        float s2 = v.x * v.x + v.y * v.y + v.z * v.z + v.w * v.w;
#pragma unroll
        for (int off = 32; off; off >>= 1) {
            s  += __shfl_down(s,  off, 64);
            s2 += __shfl_down(s2, off, 64);
        }
        const int lane = t & 63, wave = t >> 6;
        if (lane == 0) { red[wave] = s; red[4 + wave] = s2; }
        __syncthreads();
        s  = red[0] + red[1] + red[2] + red[3];
        s2 = red[4] + red[5] + red[6] + red[7];
        const float mu   = s * (1.f / D_MODEL);
        const float var  = s2 * (1.f / D_MODEL) - mu * mu;
        const float rstd = rsqrtf(var + 1e-5f);
        const float4 gv = ((const float4*)gam)[t];
        const float4 bv = ((const float4*)bet)[t];
        ushort4 o;
        o.x = f2bf((v.x - mu) * rstd * gv.x + bv.x);
        o.y = f2bf((v.y - mu) * rstd * gv.y + bv.y);
        o.z = f2bf((v.z - mu) * rstd * gv.z + bv.z);
        o.w = f2bf((v.w - mu) * rstd * gv.w + bv.w);
        ((ushort4*)(xn + (size_t)row * D_MODEL))[t] = o;
    } else {
        const int id = bid - 4096;             // 0..3071
        const int z  = id >> 10;               // which W
        const int t2 = id & 1023;
        const int n0 = (t2 & 31) * 32, k0 = (t2 >> 5) * 32;
        const float* W = (z == 0) ? Wq : (z == 1) ? Wk : Wv;
        unsigned short* outw = Wt + (size_t)z * D_MODEL * D_MODEL;
        const int tx = threadIdx.x & 31, ty = threadIdx.x >> 5;
#pragma unroll
        for (int i = ty; i < 32; i += 8)
            tile[i][tx] = W[(size_t)(k0 + i) * D_MODEL + n0 + tx];
        __syncthreads();
#pragma unroll
        for (int i = ty; i < 32; i += 8)
            outw[(size_t)(n0 + i) * D_MODEL + k0 + tx] = f2bf(tile[tx][i]);
    }
}

// ------------- QKV GEMM v3: BM=64 BN=128 BK=64, DBUF 2-phase, XOR-swizzled LDS -------------
// which 0/1 (Q/K): C = xn . W^T -> bf16 [B,H,T,64]; Q scaled by 0.125*log2e.
// which 2  (V)  : operands swapped (A=Wv^T, B=xn) -> C' = V^T -> vt[b][m][t].
// 2-phase (T3-min): STAGE(buf^1, kt+1) issued BEFORE compute of buf[cur];
// one __syncthreads per K-step drains vmcnt AFTER MFMA has covered the latency.
__global__ __launch_bounds__(256) void qkv_gemm_kernel(
    const unsigned short* __restrict__ xn, const unsigned short* __restrict__ Wt,
    const float* __restrict__ bq, const float* __restrict__ bk, const float* __restrict__ bv,
    unsigned short* __restrict__ qo, unsigned short* __restrict__ ko, unsigned short* __restrict__ vt)
{
    const int which = blockIdx.x >> 3;
    const int xt = blockIdx.x & 7, yt = blockIdx.y;
    const bool vmode = (which == 2);
    const unsigned short* Aptr = vmode ? (Wt + (size_t)2 * D_MODEL * D_MODEL) : xn;
    const unsigned short* Bptr = vmode ? xn : (Wt + (size_t)which * D_MODEL * D_MODEL);
    const float* bias   = (which == 0) ? bq : (which == 1) ? bk : bv;
    const float scale   = (which == 0) ? (0.125f * LOG2E) : 1.0f;
    const int m0 = vmode ? (yt & 15) * 64 : yt * 64;
    const int n0 = vmode ? (xt + (yt >> 4) * 8) * 128 : xt * 128;

    __shared__ unsigned short As[2][64][64];   // dbuf; linear rows, XOR-swizzled content
    __shared__ unsigned short Bs[2][128][64];

    const int tid = threadIdx.x;
    const int lane = tid & 63, wave = tid >> 6;   // 4 waves, 1M x 4N
    const int wc = wave;                          // wave's 32-col slice of BN=128
    const int g = lane >> 4, c = lane & 15;

    const int srow = lane >> 3;                               // 0..7
    const int swzc = (((lane & 7) * 8) ^ ((srow & 7) * 8));   // pre-swizzled col
    const int rsw  = (c & 7) * 8;                             // read-side XOR

    f32x4 acc[4][2] = {};

    // STAGE(buf, kt): 2 A-loads + 4 B-loads per wave, linear LDS dest
#define STAGE(buf, kt)                                                                   \
    do {                                                                                 \
        _Pragma("unroll")                                                                \
        for (int i = 0; i < 2; ++i) {                                                    \
            const int r = wave * 16 + i * 8;                                             \
            const unsigned short* ga = Aptr + (size_t)(m0 + r + srow) * D_MODEL + (kt) + swzc; \
            __builtin_amdgcn_global_load_lds(                                            \
                (const __attribute__((address_space(1))) unsigned int*)ga,              \
                (__attribute__((address_space(3))) unsigned int*)(&As[(buf)][r][0]), 16, 0, 0); \
        }                                                                                \
        _Pragma("unroll")                                                                \
        for (int i = 0; i < 4; ++i) {                                                    \
            const int r = wave * 32 + i * 8;                                             \
            const unsigned short* gb = Bptr + (size_t)(n0 + r + srow) * D_MODEL + (kt) + swzc; \
            __builtin_amdgcn_global_load_lds(                                            \
                (const __attribute__((address_space(1))) unsigned int*)gb,              \
                (__attribute__((address_space(3))) unsigned int*)(&Bs[(buf)][r][0]), 16, 0, 0); \
        }                                                                                \
    } while (0)

    STAGE(0, 0);
    __syncthreads();               // prologue drain: buf0 ready

    int cur = 0;
    for (int kt = 0; kt < D_MODEL; kt += 64) {
        if (kt + 64 < D_MODEL) STAGE(cur ^ 1, kt + 64);   // in flight during MFMA

        short8 af[4][2], bf[2][2];
#pragma unroll
        for (int i = 0; i < 4; ++i) {
            const int ra = i * 16 + c;            // ra&7 == c&7
#pragma unroll
            for (int kk = 0; kk < 2; ++kk)
                af[i][kk] = *(const short8*)(&As[cur][ra][(kk * 32 + g * 8) ^ rsw]);
        }
#pragma unroll
        for (int j = 0; j < 2; ++j) {
            const int rb = wc * 32 + j * 16 + c;
#pragma unroll
            for (int kk = 0; kk < 2; ++kk)
                bf[j][kk] = *(const short8*)(&Bs[cur][rb][(kk * 32 + g * 8) ^ rsw]);
        }
#pragma unroll
        for (int kk = 0; kk < 2; ++kk)
#pragma unroll
            for (int i = 0; i < 4; ++i)
#pragma unroll
                for (int j = 0; j < 2; ++j)
                    acc[i][j] = __builtin_amdgcn_mfma_f32_16x16x32_bf16(
                        af[i][kk], bf[j][kk], acc[i][j], 0, 0, 0);

        __syncthreads();   // drains vmcnt(0): buf^1 ready; all reads of buf[cur] done
        cur ^= 1;
    }
#undef STAGE

    if (!vmode) {
        unsigned short* out = (which == 0) ? qo : ko;
#pragma unroll
        for (int j = 0; j < 2; ++j) {
            const int n = n0 + wc * 32 + j * 16 + c;
            const float bn = bias[n];
            const int h = n >> 6, dh = n & 63;
#pragma unroll
            for (int i = 0; i < 4; ++i) {
#pragma unroll
                for (int r = 0; r < 4; ++r) {
                    const int m = m0 + i * 16 + g * 4 + r;   // m = b*2048 + t
                    const int bb = m >> 11, t = m & 2047;
                    out[((size_t)(bb * NHEAD + h) * T_SEQ + t) * HDIM + dh] =
                        f2bf((acc[i][j][r] + bn) * scale);
                }
            }
        }
    } else {
#pragma unroll
        for (int i = 0; i < 4; ++i) {
#pragma unroll
            for (int r = 0; r < 4; ++r) {
                const int m = m0 + i * 16 + g * 4 + r;       // weight-out 0..1023
                const float bn = bias[m];
#pragma unroll
                for (int j = 0; j < 2; ++j) {
                    const int n = n0 + wc * 32 + j * 16 + c; // token 0..4095
                    const int bb = n >> 11, t = n & 2047;
                    vt[(size_t)bb * (D_MODEL * T_SEQ) + (size_t)m * T_SEQ + t] =
                        f2bf(acc[i][j][r] + bn);
                }
            }
        }
    }
}

// ------------- Flash attention v5 + native exp2 (R13, proven): KV-split -------------
// Grid: 512 blocks (16 q-tiles x 32 bh), XCD-chunk-swizzled, 512 threads (8 waves).
// Waves 0-3: kv in [0,1024); waves 4-7: kv in [1024,2048); same 128 q rows.
// S^T = mfma_32x32x16(K, Q); PV: O^T = mfma(V^T, P^T) with in-register P.
__global__ __launch_bounds__(512, 4) void attn_kernel(
    const unsigned short* __restrict__ qb, const unsigned short* __restrict__ kb,
    const unsigned short* __restrict__ vtb, float* __restrict__ out)
{
    const int id  = blockIdx.x;                 // 0..511
    const int swz = (id & 7) * 64 + (id >> 3);  // XCD-chunked (512 % 8 == 0)
    const int qt  = swz & 15;                   // q-tile of 128 rows
    const int bh  = swz >> 4;                   // 0..31
    const int b = bh >> 4, head = bh & 15;
    const unsigned short* Q  = qb  + (size_t)bh * T_SEQ * HDIM;
    const unsigned short* Kp = kb  + (size_t)bh * T_SEQ * HDIM;
    const unsigned short* Vt = vtb + (size_t)b * (D_MODEL * T_SEQ)
                                   + (size_t)head * (HDIM * T_SEQ);   // [64][2048]

    __shared__ __align__(16) unsigned short smem[34816];

    const int tid = threadIdx.x, lane = tid & 63, wave = tid >> 6;
    const int grp = wave >> 2, w4 = wave & 3;
    const int q = lane & 31, h = lane >> 5;
    const int kvbase = grp * (T_SEQ / 2);

    const int gtid = tid & 255;
    const int sr = gtid >> 3;            // staging row 0..31 (+32 for 2nd chunk)
    const int sc = (gtid & 7) * 8;       // staging col (elements)

    unsigned short* gbase = &smem[grp * 17408];

    // Q fragments (B-operand): lane holds Q[q][k = c*16 + h*8 + j]
    short8 qf[4];
    {
        const unsigned short* qp = Q + (size_t)(qt * 128 + w4 * 32 + q) * HDIM;
#pragma unroll
        for (int c = 0; c < 4; ++c)
            qf[c] = *(const short8*)(qp + c * 16 + h * 8);
    }

    float l_r = 0.f;
    f32x16 o[2] = {};

    // prologue: group's tile 0 -> regs -> buf 0
    const unsigned short* kp0 = Kp + (size_t)(kvbase + sr) * HDIM + sc;
    const unsigned short* vp0 = Vt + (size_t)sr * T_SEQ + kvbase + sc;
    uint4 kr0 = *(const uint4*)(kp0);
    uint4 kr1 = *(const uint4*)(kp0 + 32 * HDIM);
    uint4 vr0 = *(const uint4*)(vp0);
    uint4 vr1 = *(const uint4*)(vp0 + 32 * T_SEQ);
    w8(gbase + sr * 68 + sc, kr0);
    w8(gbase + (sr + 32) * 68 + sc, kr1);
    w8(gbase + 8704 + sr * 68 + sc, vr0);
    w8(gbase + 8704 + (sr + 32) * 68 + sc, vr1);
    kp0 += 64 * HDIM;
    vp0 += 64;

    int cur = 0;
#pragma unroll 1
    for (int t = 0; t < 16; ++t) {
        const bool more = (t + 1 < 16);
        if (more) {   // issue next-tile loads; they stay in flight across barrier
            kr0 = *(const uint4*)(kp0);
            kr1 = *(const uint4*)(kp0 + 32 * HDIM);
            vr0 = *(const uint4*)(vp0);
            vr1 = *(const uint4*)(vp0 + 32 * T_SEQ);
            kp0 += 64 * HDIM;
            vp0 += 64;
        }
        group_barrier();                       // lgkm drain only: buf[cur] ready
        const unsigned short* kbuf = gbase + cur * 4352;
        const unsigned short* vbuf = gbase + 8704 + cur * 4352;

        // S^T = K Q^T (two 32-kv blocks)
        f32x16 s0 = {}, s1 = {};
        __builtin_amdgcn_s_setprio(1);
#pragma unroll
        for (int c = 0; c < 4; ++c) {
            const short8 kf0 = read8(kbuf + (size_t)q * 68 + c * 16 + h * 8);
            const short8 kf1 = read8(kbuf + (size_t)(32 + q) * 68 + c * 16 + h * 8);
            s0 = __builtin_amdgcn_mfma_f32_32x32x16_bf16(kf0, qf[c], s0, 0, 0, 0);
            s1 = __builtin_amdgcn_mfma_f32_32x32x16_bf16(kf1, qf[c], s1, 0, 0, 0);
        }
        __builtin_amdgcn_s_setprio(0);

        // P = exp2(S) raw (no max) -- native v_exp_f32
#pragma unroll
        for (int r = 0; r < 16; ++r) { s0[r] = EXP2(s0[r]); }
#pragma unroll
        for (int r = 0; r < 16; ++r) { s1[r] = EXP2(s1[r]); }

        // row sum, packed (v_pk_add_f32 tree)
        {
            f32x2 u[8];
#pragma unroll
            for (int r = 0; r < 8; ++r) {
                f32x2 a; a[0] = s0[2*r]; a[1] = s0[2*r+1];
                f32x2 bb; bb[0] = s1[2*r]; bb[1] = s1[2*r+1];
                u[r] = a + bb;
            }
            u[0] += u[1]; u[2] += u[3]; u[4] += u[5]; u[6] += u[7];
            u[0] += u[2]; u[4] += u[6];
            u[0] += u[4];
            float rs = u[0][0] + u[0][1];
            rs += __shfl_xor(rs, 32, 64);
            l_r += rs;
        }

        // pack to bf16 words: W[u*2+p] covers kv32 {8u+4h+2p, +1}
        unsigned Wb0[8], Wb1[8];
#pragma unroll
        for (int u = 0; u < 4; ++u) {
            asm("v_cvt_pk_bf16_f32 %0, %1, %2" : "=v"(Wb0[u*2])   : "v"(s0[4*u]),   "v"(s0[4*u+1]));
            asm("v_cvt_pk_bf16_f32 %0, %1, %2" : "=v"(Wb0[u*2+1]) : "v"(s0[4*u+2]), "v"(s0[4*u+3]));
            asm("v_cvt_pk_bf16_f32 %0, %1, %2" : "=v"(Wb1[u*2])   : "v"(s1[4*u]),   "v"(s1[4*u+1]));
            asm("v_cvt_pk_bf16_f32 %0, %1, %2" : "=v"(Wb1[u*2+1]) : "v"(s1[4*u+2]), "v"(s1[4*u+3]));
        }

        // B-frags: pf[2b+m] slot (h,j) = P[kv = 16*(2b+m) + 8h + j][q]
        short8 pf[4];
#pragma unroll
        for (int m = 0; m < 2; ++m) {
            {
                const uint2v r0 = permswap(Wb0[4*m],     Wb0[4*m + 2]);
                const uint2v r1 = permswap(Wb0[4*m + 1], Wb0[4*m + 3]);
                union { unsigned u[4]; short8 s; } pw;
                pw.u[0] = r0[0]; pw.u[1] = r1[0]; pw.u[2] = r0[1]; pw.u[3] = r1[1];
                pf[m] = pw.s;
            }
            {
                const uint2v r0 = permswap(Wb1[4*m],     Wb1[4*m + 2]);
                const uint2v r1 = permswap(Wb1[4*m + 1], Wb1[4*m + 3]);
                union { unsigned u[4]; short8 s; } pw;
                pw.u[0] = r0[0]; pw.u[1] = r1[0]; pw.u[2] = r0[1]; pw.u[3] = r1[1];
                pf[2 + m] = pw.s;
            }
        }

        // O^T += V^T P^T
        __builtin_amdgcn_s_setprio(1);
#pragma unroll
        for (int dt = 0; dt < 2; ++dt) {
#pragma unroll
            for (int cp = 0; cp < 4; ++cp) {
                const short8 vf = read8(vbuf + (size_t)(dt * 32 + q) * 68 + cp * 16 + h * 8);
                o[dt] = __builtin_amdgcn_mfma_f32_32x32x16_bf16(vf, pf[cp], o[dt], 0, 0, 0);
            }
        }
        __builtin_amdgcn_s_setprio(0);

        if (more) {   // vmcnt wait lands here (compiler), not at the barrier
            unsigned short* kd = gbase + (cur ^ 1) * 4352;
            unsigned short* vd = gbase + 8704 + (cur ^ 1) * 4352;
            w8(kd + sr * 68 + sc, kr0);
            w8(kd + (sr + 32) * 68 + sc, kr1);
            w8(vd + sr * 68 + sc, vr0);
            w8(vd + (sr + 32) * 68 + sc, vr1);
        }
        cur ^= 1;
    }

    // ---- merge the two KV halves, then transpose-store ----
    __syncthreads();                                   // all LDS reads done
    float* obuf  = (float*)(void*)smem;                // [128][68] f32
    float* l_lds = ((float*)(void*)smem) + 128 * 68;   // [128] f32

    const int qrl = w4 * 32 + q;                       // local q row 0..127
    if (grp == 0) {                                    // write raw numerators + l_A
#pragma unroll
        for (int dt = 0; dt < 2; ++dt)
#pragma unroll
            for (int u = 0; u < 4; ++u) {
                float* dst = obuf + (size_t)qrl * 68 + dt * 32 + 8 * u + 4 * h;
                float2 lo; lo.x = o[dt][4*u];     lo.y = o[dt][4*u + 1];
                float2 hi; hi.x = o[dt][4*u + 2]; hi.y = o[dt][4*u + 3];
                *(float2*)dst = lo;
                *(float2*)(dst + 2) = hi;
            }
        if (h == 0) l_lds[qrl] = l_r;
    }
    __syncthreads();
    if (grp == 1) {                                    // add numerator, scale by 1/(lA+lB)
        const float invl = 1.0f / (l_lds[qrl] + l_r);
#pragma unroll
        for (int dt = 0; dt < 2; ++dt)
#pragma unroll
            for (int u = 0; u < 4; ++u) {
                float* dst = obuf + (size_t)qrl * 68 + dt * 32 + 8 * u + 4 * h;
                float2 lo = *(const float2*)dst;
                float2 hi = *(const float2*)(dst + 2);
                lo.x = (lo.x + o[dt][4*u])     * invl;
                lo.y = (lo.y + o[dt][4*u + 1]) * invl;
                hi.x = (hi.x + o[dt][4*u + 2]) * invl;
                hi.y = (hi.y + o[dt][4*u + 3]) * invl;
                *(float2*)dst = lo;
                *(float2*)(dst + 2) = hi;
            }
    }
    __syncthreads();
#pragma unroll
    for (int it = 0; it < 4; ++it) {
        const int row = it * 32 + (tid >> 4);          // 0..127
        const int col = (tid & 15) * 4;                // 0..60
        const float4 v = *(const float4*)(&obuf[(size_t)row * 68 + col]);
        *(float4*)(&out[(size_t)(b * T_SEQ + qt * 128 + row) * D_MODEL + head * HDIM + col]) = v;
    }
}

extern "C" void kernel_launch(void* const* d_in, const int* in_sizes, int n_in,
                              void* d_out, int out_size, void* d_ws, size_t ws_size,
                              hipStream_t stream)
{
    const float* x   = (const float*)d_in[0];
    const float* lng = (const float*)d_in[1];
    const float* lnb = (const float*)d_in[2];
    const float* Wq  = (const float*)d_in[3];
    const float* bq  = (const float*)d_in[4];
    const float* Wk  = (const float*)d_in[5];
    const float* bk  = (const float*)d_in[6];
    const float* Wv  = (const float*)d_in[7];
    const float* bv  = (const float*)d_in[8];
    float* out = (float*)d_out;

    // workspace layout (bf16), ~38 MB total
    unsigned short* xn = (unsigned short*)d_ws;                 // [4096][1024]
    unsigned short* Wt = xn + (size_t)4096 * 1024;              // 3 x [1024][1024] (transposed)
    unsigned short* qh = Wt + (size_t)3 * 1024 * 1024;          // [B,H,T,64]
    unsigned short* kh = qh + (size_t)4096 * 1024;
    unsigned short* vt = kh + (size_t)4096 * 1024;              // [B][1024][2048] = V^T

    ln_wcast_kernel<<<7168, 256, 0, stream>>>(x, lng, lnb, xn, Wq, Wk, Wv, Wt);
    qkv_gemm_kernel<<<dim3(24, 64), 256, 0, stream>>>(xn, Wt, bq, bk, bv, qh, kh, vt);
    attn_kernel<<<512, 512, 0, stream>>>(qh, kh, vt, out);
}

// Round 17
// 90.882 us; speedup vs baseline: 1.2308x; 1.0557x over previous
//
#include <hip/hip_runtime.h>
#include <hip/hip_bf16.h>

// SelfAttention: LN -> Q/K/V proj -> MHA (H=16, Dh=64) -> merge heads.
// B=2, T=2048, D=1024. fp32 in/out, bf16 MFMA compute.
// Attention (v5 + native exp2, proven 48.5us): swapped QK^T, 32x32x16 MFMA,
// in-register P, no-max exp2 softmax, KV-split wave-groups, dbuf LDS.
// QKV GEMM (R13 single-buf, proven) + XCD-chunk grid swizzle (T1).
// ln_wcast: W-cast vectorized (float4 load / ushort4 store).

typedef __attribute__((ext_vector_type(8)))  short short8;    // 8 bf16
typedef __attribute__((ext_vector_type(4)))  float f32x4;
typedef __attribute__((ext_vector_type(2)))  float f32x2;
typedef __attribute__((ext_vector_type(16))) float f32x16;
typedef __attribute__((ext_vector_type(2)))  unsigned int uint2v;

#define D_MODEL 1024
#define T_SEQ   2048
#define NHEAD   16
#define HDIM    64

#define LOG2E 1.4426950408889634f

#if defined(__has_builtin)
#if __has_builtin(__builtin_amdgcn_exp2f)
#define EXP2(x) __builtin_amdgcn_exp2f(x)
#endif
#if __has_builtin(__builtin_amdgcn_permlane32_swap)
#define HAVE_PERMSWAP 1
#endif
#endif
#ifndef EXP2
#define EXP2(x) exp2f(x)
#endif

__device__ __forceinline__ unsigned short f2bf(float x) {
    unsigned int u = __float_as_uint(x);
    u = (u + 0x7fffu + ((u >> 16) & 1u)) >> 16;   // RNE
    return (unsigned short)u;
}

__device__ __forceinline__ uint2v permswap(unsigned a, unsigned b) {
#ifdef HAVE_PERMSWAP
    return __builtin_amdgcn_permlane32_swap(a, b, false, false);
#else
    uint2v r;
    const unsigned as = (unsigned)__shfl_xor((int)a, 32, 64);
    const unsigned bs = (unsigned)__shfl_xor((int)b, 32, 64);
    const bool hi = (threadIdx.x & 32) != 0;
    r[0] = hi ? bs : a;
    r[1] = hi ? b  : as;
    return r;
#endif
}

// Barrier that does NOT drain vmcnt: LDS producer/consumer ordering only.
__device__ __forceinline__ void group_barrier() {
    asm volatile("s_waitcnt lgkmcnt(0)" ::: "memory");
    __builtin_amdgcn_s_barrier();
    asm volatile("" ::: "memory");
}

__device__ __forceinline__ void w8(unsigned short* p, const uint4 v) {
    uint2 a; a.x = v.x; a.y = v.y;
    uint2 b; b.x = v.z; b.y = v.w;
    *(uint2*)p = a;
    *(uint2*)(p + 4) = b;
}

__device__ __forceinline__ short8 read8(const unsigned short* p) {
    union { unsigned u[4]; short8 s; } r;
    const uint2 a = *(const uint2*)p;
    const uint2 b = *(const uint2*)(p + 4);
    r.u[0] = a.x; r.u[1] = a.y; r.u[2] = b.x; r.u[3] = b.y;
    return r.s;
}

// ---------------- Fused LayerNorm + weight cast/transpose ----------------
// Blocks 0..4095: LN row -> bf16 xn. Blocks 4096..7167: W[k][n] f32 -> Wt[n][k] bf16.
__global__ __launch_bounds__(256) void ln_wcast_kernel(
    const float* __restrict__ x, const float* __restrict__ gam,
    const float* __restrict__ bet, unsigned short* __restrict__ xn,
    const float* __restrict__ Wq, const float* __restrict__ Wk,
    const float* __restrict__ Wv, unsigned short* __restrict__ Wt)
{
    __shared__ float red[8];
    __shared__ float tile[32][33];
    const int bid = blockIdx.x;
    if (bid < 4096) {
        const int row = bid;
        const int t = threadIdx.x;
        const float4 v = ((const float4*)(x + (size_t)row * D_MODEL))[t];
        float s  = v.x + v.y + v.z + v.w;
        float s2 = v.x * v.x + v.y * v.y + v.z * v.z + v.w * v.w;
#pragma unroll
        for (int off = 32; off; off >>= 1) {
            s  += __shfl_down(s,  off, 64);
            s2 += __shfl_down(s2, off, 64);
        }
        const int lane = t & 63, wave = t >> 6;
        if (lane == 0) { red[wave] = s; red[4 + wave] = s2; }
        __syncthreads();
        s  = red[0] + red[1] + red[2] + red[3];
        s2 = red[4] + red[5] + red[6] + red[7];
        const float mu   = s * (1.f / D_MODEL);
        const float var  = s2 * (1.f / D_MODEL) - mu * mu;
        const float rstd = rsqrtf(var + 1e-5f);
        const float4 gv = ((const float4*)gam)[t];
        const float4 bv = ((const float4*)bet)[t];
        ushort4 o;
        o.x = f2bf((v.x - mu) * rstd * gv.x + bv.x);
        o.y = f2bf((v.y - mu) * rstd * gv.y + bv.y);
        o.z = f2bf((v.z - mu) * rstd * gv.z + bv.z);
        o.w = f2bf((v.w - mu) * rstd * gv.w + bv.w);
        ((ushort4*)(xn + (size_t)row * D_MODEL))[t] = o;
    } else {
        const int id = bid - 4096;             // 0..3071
        const int z  = id >> 10;               // which W
        const int t2 = id & 1023;
        const int n0 = (t2 & 31) * 32, k0 = (t2 >> 5) * 32;
        const float* W = (z == 0) ? Wq : (z == 1) ? Wk : Wv;
        unsigned short* outw = Wt + (size_t)z * D_MODEL * D_MODEL;
        // load: lane covers float4 of W row; 256 threads = full 32x32 tile
        const int lk = threadIdx.x >> 3;           // 0..31 (k row)
        const int ln = (threadIdx.x & 7) * 4;      // 0..28 (n col, x4)
        *(float4*)&tile[lk][ln] =
            *(const float4*)&W[(size_t)(k0 + lk) * D_MODEL + n0 + ln];
        __syncthreads();
        // store: lane covers ushort4 of Wt row (k contiguous)
        const int wn = threadIdx.x >> 3;           // 0..31 (n row of Wt)
        const int wk = (threadIdx.x & 7) * 4;      // 0..28 (k col, x4)
        ushort4 o4;
        o4.x = f2bf(tile[wk + 0][wn]);
        o4.y = f2bf(tile[wk + 1][wn]);
        o4.z = f2bf(tile[wk + 2][wn]);
        o4.w = f2bf(tile[wk + 3][wn]);
        *(ushort4*)&outw[(size_t)(n0 + wn) * D_MODEL + k0 + wk] = o4;
    }
}

// ------------- QKV GEMM (R13): BM=64 BN=128 BK=64, single-buf, XOR-swizzled LDS -------------
// Grid: 1536 1-D, XCD-chunk swizzled (1536 = 8 x 192; bijective).
// which 0/1 (Q/K): C = xn . W^T -> bf16 [B,H,T,64]; Q scaled by 0.125*log2e.
// which 2  (V)  : operands swapped (A=Wv^T, B=xn) -> C' = V^T -> vt[b][m][t].
__global__ __launch_bounds__(256) void qkv_gemm_kernel(
    const unsigned short* __restrict__ xn, const unsigned short* __restrict__ Wt,
    const float* __restrict__ bq, const float* __restrict__ bk, const float* __restrict__ bv,
    unsigned short* __restrict__ qo, unsigned short* __restrict__ ko, unsigned short* __restrict__ vt)
{
    const int id  = blockIdx.x;                  // 0..1535
    const int swz = (id & 7) * 192 + (id >> 3);  // XCD chunk of 192 blocks
    const int bx  = swz % 24;                    // which*8 + xt (x-fastest: A-panel reuse)
    const int yt  = swz / 24;                    // 0..63
    const int which = bx >> 3;
    const int xt = bx & 7;
    const bool vmode = (which == 2);
    const unsigned short* Aptr = vmode ? (Wt + (size_t)2 * D_MODEL * D_MODEL) : xn;
    const unsigned short* Bptr = vmode ? xn : (Wt + (size_t)which * D_MODEL * D_MODEL);
    const float* bias   = (which == 0) ? bq : (which == 1) ? bk : bv;
    const float scale   = (which == 0) ? (0.125f * LOG2E) : 1.0f;
    const int m0 = vmode ? (yt & 15) * 64 : yt * 64;
    const int n0 = vmode ? (xt + (yt >> 4) * 8) * 128 : xt * 128;

    __shared__ unsigned short As[64][64];    // linear rows, content XOR-swizzled
    __shared__ unsigned short Bs[128][64];

    const int tid = threadIdx.x;
    const int lane = tid & 63, wave = tid >> 6;   // 4 waves, 1M x 4N
    const int wc = wave;                          // wave's 32-col slice of BN=128
    const int g = lane >> 4, c = lane & 15;

    const int srow = lane >> 3;                               // 0..7
    const int swzc = (((lane & 7) * 8) ^ ((srow & 7) * 8));   // pre-swizzled col
    const int rsw  = (c & 7) * 8;                             // read-side XOR

    f32x4 acc[4][2] = {};

    for (int kt = 0; kt < D_MODEL; kt += 64) {
        __syncthreads();   // previous tile fully consumed
#pragma unroll
        for (int i = 0; i < 2; ++i) {             // A: wave covers 16 rows
            const int r = wave * 16 + i * 8;
            const unsigned short* ga = Aptr + (size_t)(m0 + r + srow) * D_MODEL + kt + swzc;
            __builtin_amdgcn_global_load_lds(
                (const __attribute__((address_space(1))) unsigned int*)ga,
                (__attribute__((address_space(3))) unsigned int*)(&As[r][0]), 16, 0, 0);
        }
#pragma unroll
        for (int i = 0; i < 4; ++i) {             // B: wave covers 32 rows
            const int r = wave * 32 + i * 8;
            const unsigned short* gb = Bptr + (size_t)(n0 + r + srow) * D_MODEL + kt + swzc;
            __builtin_amdgcn_global_load_lds(
                (const __attribute__((address_space(1))) unsigned int*)gb,
                (__attribute__((address_space(3))) unsigned int*)(&Bs[r][0]), 16, 0, 0);
        }
        __syncthreads();   // vmcnt(0) drain + barrier -> LDS ready

        short8 af[4][2], bf[2][2];
#pragma unroll
        for (int i = 0; i < 4; ++i) {
            const int ra = i * 16 + c;            // ra&7 == c&7
#pragma unroll
            for (int kk = 0; kk < 2; ++kk)
                af[i][kk] = *(const short8*)(&As[ra][(kk * 32 + g * 8) ^ rsw]);
        }
#pragma unroll
        for (int j = 0; j < 2; ++j) {
            const int rb = wc * 32 + j * 16 + c;
#pragma unroll
            for (int kk = 0; kk < 2; ++kk)
                bf[j][kk] = *(const short8*)(&Bs[rb][(kk * 32 + g * 8) ^ rsw]);
        }
#pragma unroll
        for (int kk = 0; kk < 2; ++kk)
#pragma unroll
            for (int i = 0; i < 4; ++i)
#pragma unroll
                for (int j = 0; j < 2; ++j)
                    acc[i][j] = __builtin_amdgcn_mfma_f32_16x16x32_bf16(
                        af[i][kk], bf[j][kk], acc[i][j], 0, 0, 0);
    }

    if (!vmode) {
        unsigned short* out = (which == 0) ? qo : ko;
#pragma unroll
        for (int j = 0; j < 2; ++j) {
            const int n = n0 + wc * 32 + j * 16 + c;
            const float bn = bias[n];
            const int h = n >> 6, dh = n & 63;
#pragma unroll
            for (int i = 0; i < 4; ++i) {
#pragma unroll
                for (int r = 0; r < 4; ++r) {
                    const int m = m0 + i * 16 + g * 4 + r;   // m = b*2048 + t
                    const int bb = m >> 11, t = m & 2047;
                    out[((size_t)(bb * NHEAD + h) * T_SEQ + t) * HDIM + dh] =
                        f2bf((acc[i][j][r] + bn) * scale);
                }
            }
        }
    } else {
#pragma unroll
        for (int i = 0; i < 4; ++i) {
#pragma unroll
            for (int r = 0; r < 4; ++r) {
                const int m = m0 + i * 16 + g * 4 + r;       // weight-out 0..1023
                const float bn = bias[m];
#pragma unroll
                for (int j = 0; j < 2; ++j) {
                    const int n = n0 + wc * 32 + j * 16 + c; // token 0..4095
                    const int bb = n >> 11, t = n & 2047;
                    vt[(size_t)bb * (D_MODEL * T_SEQ) + (size_t)m * T_SEQ + t] =
                        f2bf(acc[i][j][r] + bn);
                }
            }
        }
    }
}

// ------------- Flash attention v5 + native exp2 (R13, proven): KV-split -------------
// Grid: 512 blocks (16 q-tiles x 32 bh), XCD-chunk-swizzled, 512 threads (8 waves).
// Waves 0-3: kv in [0,1024); waves 4-7: kv in [1024,2048); same 128 q rows.
// S^T = mfma_32x32x16(K, Q); PV: O^T = mfma(V^T, P^T) with in-register P.
__global__ __launch_bounds__(512, 4) void attn_kernel(
    const unsigned short* __restrict__ qb, const unsigned short* __restrict__ kb,
    const unsigned short* __restrict__ vtb, float* __restrict__ out)
{
    const int id  = blockIdx.x;                 // 0..511
    const int swz = (id & 7) * 64 + (id >> 3);  // XCD-chunked (512 % 8 == 0)
    const int qt  = swz & 15;                   // q-tile of 128 rows
    const int bh  = swz >> 4;                   // 0..31
    const int b = bh >> 4, head = bh & 15;
    const unsigned short* Q  = qb  + (size_t)bh * T_SEQ * HDIM;
    const unsigned short* Kp = kb  + (size_t)bh * T_SEQ * HDIM;
    const unsigned short* Vt = vtb + (size_t)b * (D_MODEL * T_SEQ)
                                   + (size_t)head * (HDIM * T_SEQ);   // [64][2048]

    __shared__ __align__(16) unsigned short smem[34816];

    const int tid = threadIdx.x, lane = tid & 63, wave = tid >> 6;
    const int grp = wave >> 2, w4 = wave & 3;
    const int q = lane & 31, h = lane >> 5;
    const int kvbase = grp * (T_SEQ / 2);

    const int gtid = tid & 255;
    const int sr = gtid >> 3;            // staging row 0..31 (+32 for 2nd chunk)
    const int sc = (gtid & 7) * 8;       // staging col (elements)

    unsigned short* gbase = &smem[grp * 17408];

    // Q fragments (B-operand): lane holds Q[q][k = c*16 + h*8 + j]
    short8 qf[4];
    {
        const unsigned short* qp = Q + (size_t)(qt * 128 + w4 * 32 + q) * HDIM;
#pragma unroll
        for (int c = 0; c < 4; ++c)
            qf[c] = *(const short8*)(qp + c * 16 + h * 8);
    }

    float l_r = 0.f;
    f32x16 o[2] = {};

    // prologue: group's tile 0 -> regs -> buf 0
    const unsigned short* kp0 = Kp + (size_t)(kvbase + sr) * HDIM + sc;
    const unsigned short* vp0 = Vt + (size_t)sr * T_SEQ + kvbase + sc;
    uint4 kr0 = *(const uint4*)(kp0);
    uint4 kr1 = *(const uint4*)(kp0 + 32 * HDIM);
    uint4 vr0 = *(const uint4*)(vp0);
    uint4 vr1 = *(const uint4*)(vp0 + 32 * T_SEQ);
    w8(gbase + sr * 68 + sc, kr0);
    w8(gbase + (sr + 32) * 68 + sc, kr1);
    w8(gbase + 8704 + sr * 68 + sc, vr0);
    w8(gbase + 8704 + (sr + 32) * 68 + sc, vr1);
    kp0 += 64 * HDIM;
    vp0 += 64;

    int cur = 0;
#pragma unroll 1
    for (int t = 0; t < 16; ++t) {
        const bool more = (t + 1 < 16);
        if (more) {   // issue next-tile loads; they stay in flight across barrier
            kr0 = *(const uint4*)(kp0);
            kr1 = *(const uint4*)(kp0 + 32 * HDIM);
            vr0 = *(const uint4*)(vp0);
            vr1 = *(const uint4*)(vp0 + 32 * T_SEQ);
            kp0 += 64 * HDIM;
            vp0 += 64;
        }
        group_barrier();                       // lgkm drain only: buf[cur] ready
        const unsigned short* kbuf = gbase + cur * 4352;
        const unsigned short* vbuf = gbase + 8704 + cur * 4352;

        // S^T = K Q^T (two 32-kv blocks)
        f32x16 s0 = {}, s1 = {};
        __builtin_amdgcn_s_setprio(1);
#pragma unroll
        for (int c = 0; c < 4; ++c) {
            const short8 kf0 = read8(kbuf + (size_t)q * 68 + c * 16 + h * 8);
            const short8 kf1 = read8(kbuf + (size_t)(32 + q) * 68 + c * 16 + h * 8);
            s0 = __builtin_amdgcn_mfma_f32_32x32x16_bf16(kf0, qf[c], s0, 0, 0, 0);
            s1 = __builtin_amdgcn_mfma_f32_32x32x16_bf16(kf1, qf[c], s1, 0, 0, 0);
        }
        __builtin_amdgcn_s_setprio(0);

        // P = exp2(S) raw (no max) -- native v_exp_f32
#pragma unroll
        for (int r = 0; r < 16; ++r) { s0[r] = EXP2(s0[r]); }
#pragma unroll
        for (int r = 0; r < 16; ++r) { s1[r] = EXP2(s1[r]); }

        // row sum, packed (v_pk_add_f32 tree)
        {
            f32x2 u[8];
#pragma unroll
            for (int r = 0; r < 8; ++r) {
                f32x2 a; a[0] = s0[2*r]; a[1] = s0[2*r+1];
                f32x2 bb; bb[0] = s1[2*r]; bb[1] = s1[2*r+1];
                u[r] = a + bb;
            }
            u[0] += u[1]; u[2] += u[3]; u[4] += u[5]; u[6] += u[7];
            u[0] += u[2]; u[4] += u[6];
            u[0] += u[4];
            float rs = u[0][0] + u[0][1];
            rs += __shfl_xor(rs, 32, 64);
            l_r += rs;
        }

        // pack to bf16 words: W[u*2+p] covers kv32 {8u+4h+2p, +1}
        unsigned Wb0[8], Wb1[8];
#pragma unroll
        for (int u = 0; u < 4; ++u) {
            asm("v_cvt_pk_bf16_f32 %0, %1, %2" : "=v"(Wb0[u*2])   : "v"(s0[4*u]),   "v"(s0[4*u+1]));
            asm("v_cvt_pk_bf16_f32 %0, %1, %2" : "=v"(Wb0[u*2+1]) : "v"(s0[4*u+2]), "v"(s0[4*u+3]));
            asm("v_cvt_pk_bf16_f32 %0, %1, %2" : "=v"(Wb1[u*2])   : "v"(s1[4*u]),   "v"(s1[4*u+1]));
            asm("v_cvt_pk_bf16_f32 %0, %1, %2" : "=v"(Wb1[u*2+1]) : "v"(s1[4*u+2]), "v"(s1[4*u+3]));
        }

        // B-frags: pf[2b+m] slot (h,j) = P[kv = 16*(2b+m) + 8h + j][q]
        short8 pf[4];
#pragma unroll
        for (int m = 0; m < 2; ++m) {
            {
                const uint2v r0 = permswap(Wb0[4*m],     Wb0[4*m + 2]);
                const uint2v r1 = permswap(Wb0[4*m + 1], Wb0[4*m + 3]);
                union { unsigned u[4]; short8 s; } pw;
                pw.u[0] = r0[0]; pw.u[1] = r1[0]; pw.u[2] = r0[1]; pw.u[3] = r1[1];
                pf[m] = pw.s;
            }
            {
                const uint2v r0 = permswap(Wb1[4*m],     Wb1[4*m + 2]);
                const uint2v r1 = permswap(Wb1[4*m + 1], Wb1[4*m + 3]);
                union { unsigned u[4]; short8 s; } pw;
                pw.u[0] = r0[0]; pw.u[1] = r1[0]; pw.u[2] = r0[1]; pw.u[3] = r1[1];
                pf[2 + m] = pw.s;
            }
        }

        // O^T += V^T P^T
        __builtin_amdgcn_s_setprio(1);
#pragma unroll
        for (int dt = 0; dt < 2; ++dt) {
#pragma unroll
            for (int cp = 0; cp < 4; ++cp) {
                const short8 vf = read8(vbuf + (size_t)(dt * 32 + q) * 68 + cp * 16 + h * 8);
                o[dt] = __builtin_amdgcn_mfma_f32_32x32x16_bf16(vf, pf[cp], o[dt], 0, 0, 0);
            }
        }
        __builtin_amdgcn_s_setprio(0);

        if (more) {   // vmcnt wait lands here (compiler), not at the barrier
            unsigned short* kd = gbase + (cur ^ 1) * 4352;
            unsigned short* vd = gbase + 8704 + (cur ^ 1) * 4352;
            w8(kd + sr * 68 + sc, kr0);
            w8(kd + (sr + 32) * 68 + sc, kr1);
            w8(vd + sr * 68 + sc, vr0);
            w8(vd + (sr + 32) * 68 + sc, vr1);
        }
        cur ^= 1;
    }

    // ---- merge the two KV halves, then transpose-store ----
    __syncthreads();                                   // all LDS reads done
    float* obuf  = (float*)(void*)smem;                // [128][68] f32
    float* l_lds = ((float*)(void*)smem) + 128 * 68;   // [128] f32

    const int qrl = w4 * 32 + q;                       // local q row 0..127
    if (grp == 0) {                                    // write raw numerators + l_A
#pragma unroll
        for (int dt = 0; dt < 2; ++dt)
#pragma unroll
            for (int u = 0; u < 4; ++u) {
                float* dst = obuf + (size_t)qrl * 68 + dt * 32 + 8 * u + 4 * h;
                float2 lo; lo.x = o[dt][4*u];     lo.y = o[dt][4*u + 1];
                float2 hi; hi.x = o[dt][4*u + 2]; hi.y = o[dt][4*u + 3];
                *(float2*)dst = lo;
                *(float2*)(dst + 2) = hi;
            }
        if (h == 0) l_lds[qrl] = l_r;
    }
    __syncthreads();
    if (grp == 1) {                                    // add numerator, scale by 1/(lA+lB)
        const float invl = 1.0f / (l_lds[qrl] + l_r);
#pragma unroll
        for (int dt = 0; dt < 2; ++dt)
#pragma unroll
            for (int u = 0; u < 4; ++u) {
                float* dst = obuf + (size_t)qrl * 68 + dt * 32 + 8 * u + 4 * h;
                float2 lo = *(const float2*)dst;
                float2 hi = *(const float2*)(dst + 2);
                lo.x = (lo.x + o[dt][4*u])     * invl;
                lo.y = (lo.y + o[dt][4*u + 1]) * invl;
                hi.x = (hi.x + o[dt][4*u + 2]) * invl;
                hi.y = (hi.y + o[dt][4*u + 3]) * invl;
                *(float2*)dst = lo;
                *(float2*)(dst + 2) = hi;
            }
    }
    __syncthreads();
#pragma unroll
    for (int it = 0; it < 4; ++it) {
        const int row = it * 32 + (tid >> 4);          // 0..127
        const int col = (tid & 15) * 4;                // 0..60
        const float4 v = *(const float4*)(&obuf[(size_t)row * 68 + col]);
        *(float4*)(&out[(size_t)(b * T_SEQ + qt * 128 + row) * D_MODEL + head * HDIM + col]) = v;
    }
}

extern "C" void kernel_launch(void* const* d_in, const int* in_sizes, int n_in,
                              void* d_out, int out_size, void* d_ws, size_t ws_size,
                              hipStream_t stream)
{
    const float* x   = (const float*)d_in[0];
    const float* lng = (const float*)d_in[1];
    const float* lnb = (const float*)d_in[2];
    const float* Wq  = (const float*)d_in[3];
    const float* bq  = (const float*)d_in[4];
    const float* Wk  = (const float*)d_in[5];
    const float* bk  = (const float*)d_in[6];
    const float* Wv  = (const float*)d_in[7];
    const float* bv  = (const float*)d_in[8];
    float* out = (float*)d_out;

    // workspace layout (bf16), ~38 MB total
    unsigned short* xn = (unsigned short*)d_ws;                 // [4096][1024]
    unsigned short* Wt = xn + (size_t)4096 * 1024;              // 3 x [1024][1024] (transposed)
    unsigned short* qh = Wt + (size_t)3 * 1024 * 1024;          // [B,H,T,64]
    unsigned short* kh = qh + (size_t)4096 * 1024;
    unsigned short* vt = kh + (size_t)4096 * 1024;              // [B][1024][2048] = V^T

    ln_wcast_kernel<<<7168, 256, 0, stream>>>(x, lng, lnb, xn, Wq, Wk, Wv, Wt);
    qkv_gemm_kernel<<<1536, 256, 0, stream>>>(xn, Wt, bq, bk, bv, qh, kh, vt);
    attn_kernel<<<512, 512, 0, stream>>>(qh, kh, vt, out);
}